// Round 4
// baseline (269.653 us; speedup 1.0000x reference)
//
#include <hip/hip_runtime.h>
#include <math.h>

#define TH 320
#define IMG 4

// ---- LDS float offsets (8896 floats = 35.6 KB -> 4 blocks/CU) ----
#define S_P1   0        // 4*1180 (image stride 1180, channel stride 196)
#define S_W2   4720     // 2400
#define S_P2   7120     // 4*404 = 1616
#define S_W1   8736     // 150
#define LDS_TOT 8896
// fc scratch aliases P1 region after conv2 (p1 dead):
#define S_FC1P 0        // 960
#define S_FC1  960      // 480
#define S_FC2  1440     // 336
#define S_LOG  1776     // 40

// NOTE: no min-waves arg — round 3 showed __launch_bounds__(320,5) caps VGPR at 48
// and spills ~46 live floats of conv1 state to scratch (WRITE_SIZE 0.64->70 MB).
__global__ __launch_bounds__(TH) void lenet_kernel(
    const float* __restrict__ x,
    const float* __restrict__ w1,
    const float* __restrict__ w2,
    const float* __restrict__ fw1,
    const float* __restrict__ fw2,
    const float* __restrict__ fc3w,
    const float* __restrict__ fc3b,
    float* __restrict__ out)
{
    __shared__ __align__(16) float lds[LDS_TOT];
    const int tid = threadIdx.x;
    const int blk = blockIdx.x;

    // ---- stage conv weights into LDS (x stays in global, served by L1/L2) ----
    {
        const float4* wsrc = (const float4*)w2;
        for (int e = tid; e < 600; e += TH)
            *(float4*)(lds + S_W2 + e * 4) = wsrc[e];
        for (int e = tid; e < 150; e += TH) lds[S_W1 + e] = w1[e];
    }
    __syncthreads();

    // ---- conv1 (1->6, 5x5, 28x28) + relu + pool -> p1 in LDS ----
    // task = (m, c, i, half): 7 pooled outputs; 672 tasks
    for (int task = tid; task < IMG * 168; task += TH) {
        int m = task / 168;
        int r = task - m * 168;
        int c = r % 6;           // c innermost: x addr independent of c -> L1 broadcast
        int q = r / 6;           // 0..27
        int i = q >> 1;          // pooled row 0..13
        int half = q & 1;        // cols 7*half..7*half+6

        const float* xm = x + ((size_t)(blk * IMG + m)) * 1024 + half * 14;
        const float* wc = lds + S_W1 + c * 25;

        float acc0[14], acc1[14];
        #pragma unroll
        for (int j = 0; j < 14; ++j) { acc0[j] = 0.f; acc1[j] = 0.f; }

        #pragma unroll
        for (int t = 0; t < 6; ++t) {
            float row[18];
            const float* rp = xm + (2 * i + t) * 32;
            #pragma unroll
            for (int qq = 0; qq < 9; ++qq) {
                float2 v = *(const float2*)(rp + 2 * qq);
                row[2 * qq] = v.x; row[2 * qq + 1] = v.y;
            }
            if (t < 5) {
                #pragma unroll
                for (int kx = 0; kx < 5; ++kx) {
                    float w = wc[t * 5 + kx];
                    #pragma unroll
                    for (int xx = 0; xx < 14; ++xx)
                        acc0[xx] = fmaf(row[xx + kx], w, acc0[xx]);
                }
            }
            if (t >= 1) {
                #pragma unroll
                for (int kx = 0; kx < 5; ++kx) {
                    float w = wc[(t - 1) * 5 + kx];
                    #pragma unroll
                    for (int xx = 0; xx < 14; ++xx)
                        acc1[xx] = fmaf(row[xx + kx], w, acc1[xx]);
                }
            }
        }
        float* dst = lds + S_P1 + m * 1180 + c * 196 + i * 14 + half * 7;
        #pragma unroll
        for (int j = 0; j < 7; ++j) {
            float v = fmaxf(fmaxf(acc0[2 * j], acc0[2 * j + 1]),
                            fmaxf(acc1[2 * j], acc1[2 * j + 1]));
            dst[j] = fmaxf(v, 0.f);
        }
    }
    __syncthreads();

    // ---- conv2 (6->16, 5x5) + relu + pool: exactly 1 task per thread ----
    {
        int m = tid / 80;
        int r = tid - m * 80;
        int oc = r % 16;          // oc innermost -> LDS input reads broadcast
        int i  = r / 16;          // pooled row 0..4
        const float* pim = lds + S_P1 + m * 1180;
        const float* wb  = lds + S_W2 + oc * 150;
        float acc0[10], acc1[10];
        #pragma unroll
        for (int j = 0; j < 10; ++j) { acc0[j] = 0.f; acc1[j] = 0.f; }
        for (int ic = 0; ic < 6; ++ic) {
            const float* pc = pim + ic * 196;
            const float* wc = wb + ic * 25;
            #pragma unroll
            for (int t = 0; t < 6; ++t) {
                float row[14];
                const float* rp = pc + (2 * i + t) * 14;
                #pragma unroll
                for (int qq = 0; qq < 7; ++qq) {
                    float2 v = *(const float2*)(rp + 2 * qq);
                    row[2 * qq] = v.x; row[2 * qq + 1] = v.y;
                }
                if (t < 5) {
                    #pragma unroll
                    for (int kx = 0; kx < 5; ++kx) {
                        float w = wc[t * 5 + kx];
                        #pragma unroll
                        for (int xx = 0; xx < 10; ++xx)
                            acc0[xx] = fmaf(row[xx + kx], w, acc0[xx]);
                    }
                }
                if (t >= 1) {
                    #pragma unroll
                    for (int kx = 0; kx < 5; ++kx) {
                        float w = wc[(t - 1) * 5 + kx];
                        #pragma unroll
                        for (int xx = 0; xx < 10; ++xx)
                            acc1[xx] = fmaf(row[xx + kx], w, acc1[xx]);
                    }
                }
            }
        }
        float* dst = lds + S_P2 + m * 404 + oc * 25 + i * 5;
        #pragma unroll
        for (int j = 0; j < 5; ++j) {
            float v = fmaxf(fmaxf(acc0[2 * j], acc0[2 * j + 1]),
                            fmaxf(acc1[2 * j], acc1[2 * j + 1]));
            dst[j] = fmaxf(v, 0.f);
        }
    }
    __syncthreads();

    // ---- fc1 partials: 960 tasks = 3 exact passes. task = (m, n, k-half) ----
    for (int t = tid; t < 960; t += TH) {
        int m = t & 3;
        int s = t >> 2;
        int n = s % 120;
        int h = s / 120;
        const float4* a = (const float4*)(lds + S_P2 + m * 404 + h * 200);
        const float4* w = (const float4*)(fw1 + n * 400 + h * 200);
        float acc = 0.f;
        #pragma unroll 5
        for (int k = 0; k < 50; ++k) {
            float4 av = a[k], wv = w[k];
            acc = fmaf(av.x, wv.x, acc);
            acc = fmaf(av.y, wv.y, acc);
            acc = fmaf(av.z, wv.z, acc);
            acc = fmaf(av.w, wv.w, acc);
        }
        lds[S_FC1P + (m * 120 + n) * 2 + h] = acc;
    }
    __syncthreads();

    // ---- fc1 reduce + relu ----
    for (int e = tid; e < 480; e += TH)
        lds[S_FC1 + e] = fmaxf(lds[S_FC1P + 2 * e] + lds[S_FC1P + 2 * e + 1], 0.f);
    __syncthreads();

    // ---- fc2: 336 tasks ----
    for (int t = tid; t < 336; t += TH) {
        int m = t & 3;
        int n = t >> 2;
        const float4* a = (const float4*)(lds + S_FC1 + m * 120);
        const float4* w = (const float4*)(fw2 + n * 120);
        float acc = 0.f;
        #pragma unroll
        for (int k = 0; k < 30; ++k) {
            float4 av = a[k], wv = w[k];
            acc = fmaf(av.x, wv.x, acc);
            acc = fmaf(av.y, wv.y, acc);
            acc = fmaf(av.z, wv.z, acc);
            acc = fmaf(av.w, wv.w, acc);
        }
        lds[S_FC2 + m * 84 + n] = fmaxf(acc, 0.f);
    }
    __syncthreads();

    // ---- fc3: 40 tasks ----
    if (tid < 40) {
        int m = tid & 3;
        int n = tid >> 2;
        const float4* a = (const float4*)(lds + S_FC2 + m * 84);
        const float4* w = (const float4*)(fc3w + n * 84);
        float acc = fc3b[n];
        #pragma unroll
        for (int k = 0; k < 21; ++k) {
            float4 av = a[k], wv = w[k];
            acc = fmaf(av.x, wv.x, acc);
            acc = fmaf(av.y, wv.y, acc);
            acc = fmaf(av.z, wv.z, acc);
            acc = fmaf(av.w, wv.w, acc);
        }
        lds[S_LOG + m * 10 + n] = acc;
    }
    __syncthreads();

    // ---- softmax, one thread per image ----
    if (tid < IMG) {
        const float* lg = lds + S_LOG + tid * 10;
        float mx = lg[0];
        #pragma unroll
        for (int n = 1; n < 10; ++n) mx = fmaxf(mx, lg[n]);
        float e[10]; float sum = 0.f;
        #pragma unroll
        for (int n = 0; n < 10; ++n) { e[n] = expf(lg[n] - mx); sum += e[n]; }
        float inv = 1.f / sum;
        float* op = out + ((size_t)blk * IMG + tid) * 10;
        #pragma unroll
        for (int n = 0; n < 10; ++n) op[n] = e[n] * inv;
    }
}

extern "C" void kernel_launch(void* const* d_in, const int* in_sizes, int n_in,
                              void* d_out, int out_size, void* d_ws, size_t ws_size,
                              hipStream_t stream) {
    const float* x    = (const float*)d_in[0];
    const float* w1   = (const float*)d_in[1];
    const float* w2   = (const float*)d_in[2];
    const float* fw1  = (const float*)d_in[3];
    const float* fw2  = (const float*)d_in[4];
    const float* fc3w = (const float*)d_in[5];
    const float* fc3b = (const float*)d_in[6];
    float* outp = (float*)d_out;

    dim3 grid(16384 / IMG), block(TH);
    hipLaunchKernelGGL(lenet_kernel, grid, block, 0, stream,
                       x, w1, w2, fw1, fw2, fc3w, fc3b, outp);
}

// Round 5
// 213.832 us; speedup vs baseline: 1.2610x; 1.2610x over previous
//
#include <hip/hip_runtime.h>
#include <math.h>

#define TH 256
#define IMG 6

// ---- LDS float offsets (12064 floats = 48.3 KB -> 3 blocks/CU) ----
// Region A (0..7080): x staged (6*1152=6912) -> overwritten by p1 (6*1180=7080)
//                     -> after conv2, fc scratch.
// Region B (7080..9504): p2 (6*404=2424)
#define S_A    0
#define S_B    7080
#define S_W2   9504     // 2400
#define S_W1   11904    // 150
#define LDS_TOT 12064
// fc scratch inside region A (p1 dead once conv2 finishes):
#define S_FC1P 0        // 1440
#define S_FC1  1440     // 720
#define S_FC2  2160     // 504
#define S_LOG  2664     // 60

// NOTE: no min-waves arg (round 3: (320,5) capped VGPR=48 -> scratch spill storm).
__global__ __launch_bounds__(TH) void lenet_kernel(
    const float* __restrict__ x,
    const float* __restrict__ w1,
    const float* __restrict__ w2,
    const float* __restrict__ fw1,
    const float* __restrict__ fw2,
    const float* __restrict__ fc3w,
    const float* __restrict__ fc3b,
    float* __restrict__ out)
{
    __shared__ __align__(16) float lds[LDS_TOT];
    const int tid = threadIdx.x;
    const int blk = blockIdx.x;

    // ---- stage x (6 images, row stride 36) + conv weights into LDS ----
    {
        for (int e = tid; e < IMG * 256; e += TH) {      // 1536 float4
            int m = e >> 8;
            int rem = e & 255;
            int y = rem >> 3;
            int k = rem & 7;
            int gm = blk * IMG + m;
            float4 v = make_float4(0.f, 0.f, 0.f, 0.f);
            if (gm < 16384)
                v = ((const float4*)(x + (size_t)gm * 1024))[rem];
            *(float4*)(lds + S_A + m * 1152 + y * 36 + k * 4) = v;
        }
        const float4* wsrc = (const float4*)w2;
        for (int e = tid; e < 600; e += TH)
            *(float4*)(lds + S_W2 + e * 4) = wsrc[e];
        for (int e = tid; e < 150; e += TH) lds[S_W1 + e] = w1[e];
    }
    __syncthreads();

    // ---- conv1 (1->6, 5x5) + relu + pool: results held in registers ----
    // task = (m, c, i, half): 7 pooled outputs; 1008 tasks = 3.94 passes
    float rr[4][7];
    #pragma unroll
    for (int pass = 0; pass < 4; ++pass) {
        int task = tid + pass * TH;
        if (task >= IMG * 168) break;
        int m = task / 168;
        int r = task - m * 168;
        int c = r % 6;           // c innermost: x addr independent of c -> broadcast
        int q = r / 6;
        int i = q >> 1;          // pooled row 0..13
        int half = q & 1;        // cols 7*half..7*half+6

        const float* xm = lds + S_A + m * 1152 + half * 14;
        const float* wc = lds + S_W1 + c * 25;

        float acc0[14], acc1[14];
        #pragma unroll
        for (int j = 0; j < 14; ++j) { acc0[j] = 0.f; acc1[j] = 0.f; }

        #pragma unroll
        for (int t = 0; t < 6; ++t) {
            float row[18];
            const float* rp = xm + (2 * i + t) * 36;
            #pragma unroll
            for (int qq = 0; qq < 9; ++qq) {
                float2 v = *(const float2*)(rp + 2 * qq);
                row[2 * qq] = v.x; row[2 * qq + 1] = v.y;
            }
            if (t < 5) {
                #pragma unroll
                for (int kx = 0; kx < 5; ++kx) {
                    float w = wc[t * 5 + kx];
                    #pragma unroll
                    for (int xx = 0; xx < 14; ++xx)
                        acc0[xx] = fmaf(row[xx + kx], w, acc0[xx]);
                }
            }
            if (t >= 1) {
                #pragma unroll
                for (int kx = 0; kx < 5; ++kx) {
                    float w = wc[(t - 1) * 5 + kx];
                    #pragma unroll
                    for (int xx = 0; xx < 14; ++xx)
                        acc1[xx] = fmaf(row[xx + kx], w, acc1[xx]);
                }
            }
        }
        #pragma unroll
        for (int j = 0; j < 7; ++j) {
            float v = fmaxf(fmaxf(acc0[2 * j], acc0[2 * j + 1]),
                            fmaxf(acc1[2 * j], acc1[2 * j + 1]));
            rr[pass][j] = fmaxf(v, 0.f);
        }
    }
    __syncthreads();   // all x reads done -> safe to overwrite region A with p1

    #pragma unroll
    for (int pass = 0; pass < 4; ++pass) {
        int task = tid + pass * TH;
        if (task >= IMG * 168) break;
        int m = task / 168;
        int r = task - m * 168;
        int c = r % 6;
        int q = r / 6;
        int i = q >> 1;
        int half = q & 1;
        float* dst = lds + S_A + m * 1180 + c * 196 + i * 14 + half * 7;
        #pragma unroll
        for (int j = 0; j < 7; ++j) dst[j] = rr[pass][j];
    }
    __syncthreads();

    // ---- conv2 (6->16, 5x5) + relu + pool: 480 tasks = 1.875 passes ----
    #pragma unroll
    for (int pass = 0; pass < 2; ++pass) {
        int task = tid + pass * TH;
        if (task >= IMG * 80) break;
        int m = task / 80;
        int r = task - m * 80;
        int oc = r % 16;          // oc innermost -> p1 reads broadcast
        int i  = r / 16;          // pooled row 0..4
        const float* pim = lds + S_A + m * 1180;
        const float* wb  = lds + S_W2 + oc * 150;
        float acc0[10], acc1[10];
        #pragma unroll
        for (int j = 0; j < 10; ++j) { acc0[j] = 0.f; acc1[j] = 0.f; }
        for (int ic = 0; ic < 6; ++ic) {
            const float* pc = pim + ic * 196;
            const float* wc = wb + ic * 25;
            #pragma unroll
            for (int t = 0; t < 6; ++t) {
                float row[14];
                const float* rp = pc + (2 * i + t) * 14;
                #pragma unroll
                for (int qq = 0; qq < 7; ++qq) {
                    float2 v = *(const float2*)(rp + 2 * qq);
                    row[2 * qq] = v.x; row[2 * qq + 1] = v.y;
                }
                if (t < 5) {
                    #pragma unroll
                    for (int kx = 0; kx < 5; ++kx) {
                        float w = wc[t * 5 + kx];
                        #pragma unroll
                        for (int xx = 0; xx < 10; ++xx)
                            acc0[xx] = fmaf(row[xx + kx], w, acc0[xx]);
                    }
                }
                if (t >= 1) {
                    #pragma unroll
                    for (int kx = 0; kx < 5; ++kx) {
                        float w = wc[(t - 1) * 5 + kx];
                        #pragma unroll
                        for (int xx = 0; xx < 10; ++xx)
                            acc1[xx] = fmaf(row[xx + kx], w, acc1[xx]);
                    }
                }
            }
        }
        float* dst = lds + S_B + m * 404 + oc * 25 + i * 5;   // p2: k = oc*25+i*5+j
        #pragma unroll
        for (int j = 0; j < 5; ++j) {
            float v = fmaxf(fmaxf(acc0[2 * j], acc0[2 * j + 1]),
                            fmaxf(acc1[2 * j], acc1[2 * j + 1]));
            dst[j] = fmaxf(v, 0.f);
        }
    }
    __syncthreads();   // p1 dead from here; region A becomes fc scratch

    // ---- fc1 partials: task = (m inner, n, k-half h); 1440 = 5.625 passes ----
    for (int t = tid; t < IMG * 120 * 2; t += TH) {
        int m = t % 6;
        int s = t / 6;
        int n = s % 120;
        int h = s / 120;
        const float4* a = (const float4*)(lds + S_B + m * 404 + h * 200);
        const float4* w = (const float4*)(fw1 + n * 400 + h * 200);
        float acc = 0.f;
        #pragma unroll 5
        for (int k = 0; k < 50; ++k) {
            float4 av = a[k], wv = w[k];
            acc = fmaf(av.x, wv.x, acc);
            acc = fmaf(av.y, wv.y, acc);
            acc = fmaf(av.z, wv.z, acc);
            acc = fmaf(av.w, wv.w, acc);
        }
        lds[S_FC1P + (m * 120 + n) * 2 + h] = acc;
    }
    __syncthreads();

    // ---- fc1 reduce + relu: 720 elems ----
    for (int e = tid; e < IMG * 120; e += TH)
        lds[S_FC1 + e] = fmaxf(lds[S_FC1P + 2 * e] + lds[S_FC1P + 2 * e + 1], 0.f);
    __syncthreads();

    // ---- fc2: 504 tasks ----
    for (int t = tid; t < IMG * 84; t += TH) {
        int m = t % 6;
        int n = t / 6;
        const float4* a = (const float4*)(lds + S_FC1 + m * 120);
        const float4* w = (const float4*)(fw2 + n * 120);
        float acc = 0.f;
        #pragma unroll
        for (int k = 0; k < 30; ++k) {
            float4 av = a[k], wv = w[k];
            acc = fmaf(av.x, wv.x, acc);
            acc = fmaf(av.y, wv.y, acc);
            acc = fmaf(av.z, wv.z, acc);
            acc = fmaf(av.w, wv.w, acc);
        }
        lds[S_FC2 + m * 84 + n] = fmaxf(acc, 0.f);
    }
    __syncthreads();

    // ---- fc3: 60 tasks ----
    if (tid < IMG * 10) {
        int m = tid % 6;
        int n = tid / 6;
        const float4* a = (const float4*)(lds + S_FC2 + m * 84);
        const float4* w = (const float4*)(fc3w + n * 84);
        float acc = fc3b[n];
        #pragma unroll
        for (int k = 0; k < 21; ++k) {
            float4 av = a[k], wv = w[k];
            acc = fmaf(av.x, wv.x, acc);
            acc = fmaf(av.y, wv.y, acc);
            acc = fmaf(av.z, wv.z, acc);
            acc = fmaf(av.w, wv.w, acc);
        }
        lds[S_LOG + m * 10 + n] = acc;
    }
    __syncthreads();

    // ---- softmax, one thread per image ----
    if (tid < IMG) {
        int gm = blk * IMG + tid;
        if (gm < 16384) {
            const float* lg = lds + S_LOG + tid * 10;
            float mx = lg[0];
            #pragma unroll
            for (int n = 1; n < 10; ++n) mx = fmaxf(mx, lg[n]);
            float e[10]; float sum = 0.f;
            #pragma unroll
            for (int n = 0; n < 10; ++n) { e[n] = expf(lg[n] - mx); sum += e[n]; }
            float inv = 1.f / sum;
            float* op = out + (size_t)gm * 10;
            #pragma unroll
            for (int n = 0; n < 10; ++n) op[n] = e[n] * inv;
        }
    }
}

extern "C" void kernel_launch(void* const* d_in, const int* in_sizes, int n_in,
                              void* d_out, int out_size, void* d_ws, size_t ws_size,
                              hipStream_t stream) {
    const float* x    = (const float*)d_in[0];
    const float* w1   = (const float*)d_in[1];
    const float* w2   = (const float*)d_in[2];
    const float* fw1  = (const float*)d_in[3];
    const float* fw2  = (const float*)d_in[4];
    const float* fc3w = (const float*)d_in[5];
    const float* fc3b = (const float*)d_in[6];
    float* outp = (float*)d_out;

    dim3 grid((16384 + IMG - 1) / IMG), block(TH);
    hipLaunchKernelGGL(lenet_kernel, grid, block, 0, stream,
                       x, w1, w2, fw1, fw2, fc3w, fc3b, outp);
}

// Round 6
// 211.075 us; speedup vs baseline: 1.2775x; 1.0131x over previous
//
#include <hip/hip_runtime.h>
#include <math.h>

#define TH 256
#define IMG 6

// ---- LDS float offsets (9656 floats = 38.6 KB -> 4 blocks/CU, 16 waves) ----
// Region A (0..7080): x staged (6*1152) -> p1 (6*1180) -> fc scratch.
// Region B (7080..9504): p2 (6*404 = 2424). w2 is NOT staged (global/L1, 9.6 KB).
#define S_A    0
#define S_B    7080
#define S_W1   9504     // 150
#define LDS_TOT 9656
// fc scratch inside region A (p1 dead once conv2 finishes):
#define S_FC1P 0        // 1440
#define S_FC1  1440     // 720
#define S_FC2  2160     // 504
#define S_LOG  2664     // 60

// NOTE: no min-waves arg (round 3: (320,5) capped VGPR=48 -> scratch spill storm).
__global__ __launch_bounds__(TH) void lenet_kernel(
    const float* __restrict__ x,
    const float* __restrict__ w1,
    const float* __restrict__ w2g,
    const float* __restrict__ fw1,
    const float* __restrict__ fw2,
    const float* __restrict__ fc3w,
    const float* __restrict__ fc3b,
    float* __restrict__ out)
{
    __shared__ __align__(16) float lds[LDS_TOT];
    const int tid = threadIdx.x;
    const int blk = blockIdx.x;

    // ---- stage x (6 images, row stride 36) + w1 into LDS ----
    {
        for (int e = tid; e < IMG * 256; e += TH) {      // 1536 float4
            int m = e >> 8;
            int rem = e & 255;
            int y = rem >> 3;
            int k = rem & 7;
            int gm = blk * IMG + m;
            float4 v = make_float4(0.f, 0.f, 0.f, 0.f);
            if (gm < 16384)
                v = ((const float4*)(x + (size_t)gm * 1024))[rem];
            *(float4*)(lds + S_A + m * 1152 + y * 36 + k * 4) = v;
        }
        for (int e = tid; e < 150; e += TH) lds[S_W1 + e] = w1[e];
    }
    __syncthreads();

    // ---- conv1 (1->6, 5x5) + relu + pool: results held in registers ----
    // task = (m, c, i, half): 7 pooled outputs; 1008 tasks = 3.94 passes
    float rr[4][7];
    #pragma unroll
    for (int pass = 0; pass < 4; ++pass) {
        int task = tid + pass * TH;
        if (task >= IMG * 168) break;
        int m = task / 168;
        int r = task - m * 168;
        int c = r % 6;           // c innermost: x addr independent of c -> broadcast
        int q = r / 6;
        int i = q >> 1;          // pooled row 0..13
        int half = q & 1;        // cols 7*half..7*half+6

        const float* xm = lds + S_A + m * 1152 + half * 14;
        const float* wc = lds + S_W1 + c * 25;

        float acc0[14], acc1[14];
        #pragma unroll
        for (int j = 0; j < 14; ++j) { acc0[j] = 0.f; acc1[j] = 0.f; }

        #pragma unroll
        for (int t = 0; t < 6; ++t) {
            float row[18];
            const float* rp = xm + (2 * i + t) * 36;
            #pragma unroll
            for (int qq = 0; qq < 9; ++qq) {
                float2 v = *(const float2*)(rp + 2 * qq);
                row[2 * qq] = v.x; row[2 * qq + 1] = v.y;
            }
            if (t < 5) {
                #pragma unroll
                for (int kx = 0; kx < 5; ++kx) {
                    float w = wc[t * 5 + kx];
                    #pragma unroll
                    for (int xx = 0; xx < 14; ++xx)
                        acc0[xx] = fmaf(row[xx + kx], w, acc0[xx]);
                }
            }
            if (t >= 1) {
                #pragma unroll
                for (int kx = 0; kx < 5; ++kx) {
                    float w = wc[(t - 1) * 5 + kx];
                    #pragma unroll
                    for (int xx = 0; xx < 14; ++xx)
                        acc1[xx] = fmaf(row[xx + kx], w, acc1[xx]);
                }
            }
        }
        #pragma unroll
        for (int j = 0; j < 7; ++j) {
            float v = fmaxf(fmaxf(acc0[2 * j], acc0[2 * j + 1]),
                            fmaxf(acc1[2 * j], acc1[2 * j + 1]));
            rr[pass][j] = fmaxf(v, 0.f);
        }
    }
    __syncthreads();   // all x reads done -> overwrite region A with p1

    #pragma unroll
    for (int pass = 0; pass < 4; ++pass) {
        int task = tid + pass * TH;
        if (task >= IMG * 168) break;
        int m = task / 168;
        int r = task - m * 168;
        int c = r % 6;
        int q = r / 6;
        int i = q >> 1;
        int half = q & 1;
        float* dst = lds + S_A + m * 1180 + c * 196 + i * 14 + half * 7;
        #pragma unroll
        for (int j = 0; j < 7; ++j) dst[j] = rr[pass][j];
    }
    __syncthreads();

    // ---- conv2 (6->16, 5x5) + relu + pool: 2 output channels per task ----
    // 240 tasks = single 94% pass. Rows read once per 2 oc; w2 from global (L1).
    if (tid < IMG * 40) {
        int i   = tid % 5;            // pooled row, lane-fastest for bank spread
        int ocg = (tid / 5) % 8;
        int m   = tid / 40;
        int ocA = 2 * ocg;
        const float* pim = lds + S_A + m * 1180;
        const float* wga = w2g + ocA * 150;
        const float* wgb = wga + 150;

        float acc0a[10], acc1a[10], acc0b[10], acc1b[10];
        #pragma unroll
        for (int j = 0; j < 10; ++j)
            { acc0a[j]=0.f; acc1a[j]=0.f; acc0b[j]=0.f; acc1b[j]=0.f; }

        for (int ic = 0; ic < 6; ++ic) {
            const float* pc = pim + ic * 196;
            const float* wa = wga + ic * 25;
            const float* wb = wgb + ic * 25;
            float wpa[5], wpb[5];     // previous-row weights (rolling)
            #pragma unroll
            for (int t = 0; t < 6; ++t) {
                float row[14];
                const float* rp = pc + (2 * i + t) * 14;
                #pragma unroll
                for (int qq = 0; qq < 7; ++qq) {
                    float2 v = *(const float2*)(rp + 2 * qq);
                    row[2 * qq] = v.x; row[2 * qq + 1] = v.y;
                }
                if (t < 5) {
                    float wca[5], wcb[5];
                    #pragma unroll
                    for (int kx = 0; kx < 5; ++kx)
                        { wca[kx] = wa[t * 5 + kx]; wcb[kx] = wb[t * 5 + kx]; }
                    #pragma unroll
                    for (int kx = 0; kx < 5; ++kx) {
                        #pragma unroll
                        for (int xx = 0; xx < 10; ++xx) {
                            acc0a[xx] = fmaf(row[xx + kx], wca[kx], acc0a[xx]);
                            acc0b[xx] = fmaf(row[xx + kx], wcb[kx], acc0b[xx]);
                        }
                    }
                    if (t >= 1) {
                        #pragma unroll
                        for (int kx = 0; kx < 5; ++kx) {
                            #pragma unroll
                            for (int xx = 0; xx < 10; ++xx) {
                                acc1a[xx] = fmaf(row[xx + kx], wpa[kx], acc1a[xx]);
                                acc1b[xx] = fmaf(row[xx + kx], wpb[kx], acc1b[xx]);
                            }
                        }
                    }
                    #pragma unroll
                    for (int kx = 0; kx < 5; ++kx)
                        { wpa[kx] = wca[kx]; wpb[kx] = wcb[kx]; }
                } else {  // t == 5: only acc1 with w row 4 (in wpa/wpb)
                    #pragma unroll
                    for (int kx = 0; kx < 5; ++kx) {
                        #pragma unroll
                        for (int xx = 0; xx < 10; ++xx) {
                            acc1a[xx] = fmaf(row[xx + kx], wpa[kx], acc1a[xx]);
                            acc1b[xx] = fmaf(row[xx + kx], wpb[kx], acc1b[xx]);
                        }
                    }
                }
            }
        }
        float* dstA = lds + S_B + m * 404 + ocA * 25 + i * 5;
        float* dstB = dstA + 25;
        #pragma unroll
        for (int j = 0; j < 5; ++j) {
            float va = fmaxf(fmaxf(acc0a[2*j], acc0a[2*j+1]),
                             fmaxf(acc1a[2*j], acc1a[2*j+1]));
            float vb = fmaxf(fmaxf(acc0b[2*j], acc0b[2*j+1]),
                             fmaxf(acc1b[2*j], acc1b[2*j+1]));
            dstA[j] = fmaxf(va, 0.f);
            dstB[j] = fmaxf(vb, 0.f);
        }
    }
    __syncthreads();   // p1 dead; region A becomes fc scratch

    // ---- fc1 partials: task = (n-pair, k-half); all 6 images in registers ----
    // 120 tasks; a-reads are 2-address wave broadcasts (free); each fw1 elem read once.
    if (tid < 120) {
        int np = tid >> 1;
        int h  = tid & 1;
        int n0 = 2 * np, n1 = n0 + 1;
        const float4* w0 = (const float4*)(fw1 + n0 * 400 + h * 200);
        const float4* w1v = (const float4*)(fw1 + n1 * 400 + h * 200);
        float acc0[6], acc1[6];
        #pragma unroll
        for (int m = 0; m < 6; ++m) { acc0[m] = 0.f; acc1[m] = 0.f; }
        for (int k = 0; k < 50; ++k) {
            float4 wv0 = w0[k], wv1 = w1v[k];
            #pragma unroll
            for (int m = 0; m < 6; ++m) {
                float4 av = *(const float4*)(lds + S_B + m * 404 + h * 200 + 4 * k);
                acc0[m] = fmaf(av.x, wv0.x, fmaf(av.y, wv0.y,
                          fmaf(av.z, wv0.z, fmaf(av.w, wv0.w, acc0[m]))));
                acc1[m] = fmaf(av.x, wv1.x, fmaf(av.y, wv1.y,
                          fmaf(av.z, wv1.z, fmaf(av.w, wv1.w, acc1[m]))));
            }
        }
        #pragma unroll
        for (int m = 0; m < 6; ++m) {
            lds[S_FC1P + (m * 120 + n0) * 2 + h] = acc0[m];
            lds[S_FC1P + (m * 120 + n1) * 2 + h] = acc1[m];
        }
    }
    __syncthreads();

    // ---- fc1 reduce + relu: 720 elems ----
    for (int e = tid; e < IMG * 120; e += TH)
        lds[S_FC1 + e] = fmaxf(lds[S_FC1P + 2 * e] + lds[S_FC1P + 2 * e + 1], 0.f);
    __syncthreads();

    // ---- fc2: task = n, all 6 images; a-reads broadcast ----
    if (tid < 84) {
        int n = tid;
        const float4* w = (const float4*)(fw2 + n * 120);
        float acc[6];
        #pragma unroll
        for (int m = 0; m < 6; ++m) acc[m] = 0.f;
        for (int k = 0; k < 30; ++k) {
            float4 wv = w[k];
            #pragma unroll
            for (int m = 0; m < 6; ++m) {
                float4 av = *(const float4*)(lds + S_FC1 + m * 120 + 4 * k);
                acc[m] = fmaf(av.x, wv.x, fmaf(av.y, wv.y,
                         fmaf(av.z, wv.z, fmaf(av.w, wv.w, acc[m]))));
            }
        }
        #pragma unroll
        for (int m = 0; m < 6; ++m)
            lds[S_FC2 + m * 84 + n] = fmaxf(acc[m], 0.f);
    }
    __syncthreads();

    // ---- fc3: 60 tasks ----
    if (tid < IMG * 10) {
        int n = tid / 6;
        int m = tid % 6;
        const float4* a = (const float4*)(lds + S_FC2 + m * 84);
        const float4* w = (const float4*)(fc3w + n * 84);
        float acc = fc3b[n];
        #pragma unroll
        for (int k = 0; k < 21; ++k) {
            float4 av = a[k], wv = w[k];
            acc = fmaf(av.x, wv.x, fmaf(av.y, wv.y,
                  fmaf(av.z, wv.z, fmaf(av.w, wv.w, acc))));
        }
        lds[S_LOG + m * 10 + n] = acc;
    }
    __syncthreads();

    // ---- softmax, one thread per image ----
    if (tid < IMG) {
        int gm = blk * IMG + tid;
        if (gm < 16384) {
            const float* lg = lds + S_LOG + tid * 10;
            float mx = lg[0];
            #pragma unroll
            for (int n = 1; n < 10; ++n) mx = fmaxf(mx, lg[n]);
            float e[10]; float sum = 0.f;
            #pragma unroll
            for (int n = 0; n < 10; ++n) { e[n] = expf(lg[n] - mx); sum += e[n]; }
            float inv = 1.f / sum;
            float* op = out + (size_t)gm * 10;
            #pragma unroll
            for (int n = 0; n < 10; ++n) op[n] = e[n] * inv;
        }
    }
}

extern "C" void kernel_launch(void* const* d_in, const int* in_sizes, int n_in,
                              void* d_out, int out_size, void* d_ws, size_t ws_size,
                              hipStream_t stream) {
    const float* x    = (const float*)d_in[0];
    const float* w1   = (const float*)d_in[1];
    const float* w2   = (const float*)d_in[2];
    const float* fw1  = (const float*)d_in[3];
    const float* fw2  = (const float*)d_in[4];
    const float* fc3w = (const float*)d_in[5];
    const float* fc3b = (const float*)d_in[6];
    float* outp = (float*)d_out;

    dim3 grid((16384 + IMG - 1) / IMG), block(TH);
    hipLaunchKernelGGL(lenet_kernel, grid, block, 0, stream,
                       x, w1, w2, fw1, fw2, fc3w, fc3b, outp);
}

// Round 7
// 102.740 us; speedup vs baseline: 2.6246x; 2.0545x over previous
//
#include <hip/hip_runtime.h>
#include <math.h>

#define TH 256

typedef __attribute__((ext_vector_type(8))) short short8;
typedef __attribute__((ext_vector_type(4))) float floatx4;

// ---- LDS element-index constants (total 37856 B -> 4 blocks/CU) ----
// p1 FIRST so garbage A-row reads (img 8..15) stay inside the allocation.
#define P1_S   0       // shorts: 8 img * 1176  ([img][y*84 + x*6 + ic], bf16)
#define XBUF_F 4704    // floats: 3 img * 1088  (row stride 34)
#define P2_S   9408    // shorts: 8 img * 424   (aliases xbuf; k=oc*25+i*5+j, pad 400..423=0)
#define H1_S   12800   // shorts: 8 img * 136   (aliases xbuf; pad 120..135=0)
#define H2_S   13888   // shorts: 8 img * 104   (aliases xbuf; pad 84..103=0)
#define LOG_F  7360    // floats: 8 img * 12    (aliases xbuf)
#define W1_F   7968    // floats: 150
#define BT_S   16240   // shorts: 16 oc * 168   (w2 reordered: k = dy*32 + dx*6+ic, r>=30 -> 0)
#define LDS_F  9464    // 37856 bytes

static __device__ __forceinline__ unsigned short f2bf(float x) {
    union { float f; unsigned u; } v; v.f = x;
    unsigned r = (v.u + 0x7FFFu + ((v.u >> 16) & 1u)) >> 16;   // RNE
    return (unsigned short)r;
}

// 8 fp32 weights row[kb..kb+7] -> bf16 frag, with per-quad clamp so loads stay
// in-bounds when kb+q*4 crosses K (the corresponding A slots are zero-padded).
static __device__ __forceinline__ short8 load_bf8_clamped(const float* row, int kb, int K) {
    int b0 = (kb + 4 <= K) ? kb : (K - 8);
    int b1 = (kb + 8 <= K) ? (kb + 4) : (K - 8);
    float4 w0 = *(const float4*)(row + b0);
    float4 w1 = *(const float4*)(row + b1);
    short8 b;
    b[0] = (short)f2bf(w0.x); b[1] = (short)f2bf(w0.y);
    b[2] = (short)f2bf(w0.z); b[3] = (short)f2bf(w0.w);
    b[4] = (short)f2bf(w1.x); b[5] = (short)f2bf(w1.y);
    b[6] = (short)f2bf(w1.z); b[7] = (short)f2bf(w1.w);
    return b;
}

// NOTE: no min-waves arg (round 3: (320,5) capped VGPR=48 -> scratch spill storm).
__global__ __launch_bounds__(TH) void lenet_kernel(
    const float* __restrict__ x,
    const float* __restrict__ w1,
    const float* __restrict__ w2g,
    const float* __restrict__ fw1,
    const float* __restrict__ fw2,
    const float* __restrict__ fc3w,
    const float* __restrict__ fc3b,
    float* __restrict__ out)
{
    __shared__ __align__(16) float sf[LDS_F];
    short* sh = (short*)sf;
    const int* p1i = (const int*)sf;

    const int tid  = threadIdx.x;
    const int blk  = blockIdx.x;
    const int lane = tid & 63;
    const int wid  = tid >> 6;
    const int g    = lane >> 4;     // k-group selector of MFMA frags
    const int cn   = lane & 15;     // row(A)/col(B) selector

    // ================= conv1 (fp32 VALU), 3 x-substages =================
    for (int sub = 0; sub < 3; ++sub) {
        const int nimg = (sub < 2) ? 3 : 2;
        const float* xg = x + ((size_t)blk * 8 + sub * 3) * 1024;
        for (int e = tid; e < nimg * 256; e += TH) {
            int m = e >> 8, rem = e & 255;
            int y = rem >> 3, k4 = rem & 7;
            float4 v = ((const float4*)xg)[e];
            int d = XBUF_F + m * 1088 + y * 34 + k4 * 4;
            *(float2*)(sf + d)     = make_float2(v.x, v.y);
            *(float2*)(sf + d + 2) = make_float2(v.z, v.w);
        }
        if (sub == 0) {
            for (int e = tid; e < 150; e += TH) sf[W1_F + e] = w1[e];
            // Bt[oc][dy*32 + r], r = dx*6+ic (<30), zero-pad r=30,31
            for (int e = tid; e < 2560; e += TH) {
                int oc = e / 160, kk = e - oc * 160;
                int s = kk >> 5, r = kk & 31;
                float v = 0.f;
                if (r < 30) v = w2g[oc * 150 + (r % 6) * 25 + s * 5 + (r / 6)];
                sh[BT_S + oc * 168 + kk] = (short)f2bf(v);
            }
        }
        __syncthreads();

        const int ntask = nimg * 168;
        for (int t = tid; t < ntask; t += TH) {
            int m = t / 168, r = t - m * 168;
            int c = r % 6, q = r / 6;
            int i = q >> 1, hf = q & 1;
            const float* xm = sf + XBUF_F + m * 1088 + hf * 14;
            const float* wc = sf + W1_F + c * 25;
            float acc0[14], acc1[14];
            #pragma unroll
            for (int j = 0; j < 14; ++j) { acc0[j] = 0.f; acc1[j] = 0.f; }
            #pragma unroll
            for (int tt = 0; tt < 6; ++tt) {
                float row[18];
                const float* rp = xm + (2 * i + tt) * 34;
                #pragma unroll
                for (int qq = 0; qq < 9; ++qq) {
                    float2 v2 = *(const float2*)(rp + 2 * qq);
                    row[2 * qq] = v2.x; row[2 * qq + 1] = v2.y;
                }
                if (tt < 5) {
                    #pragma unroll
                    for (int kx = 0; kx < 5; ++kx) {
                        float w = wc[tt * 5 + kx];
                        #pragma unroll
                        for (int xx = 0; xx < 14; ++xx)
                            acc0[xx] = fmaf(row[xx + kx], w, acc0[xx]);
                    }
                }
                if (tt >= 1) {
                    #pragma unroll
                    for (int kx = 0; kx < 5; ++kx) {
                        float w = wc[(tt - 1) * 5 + kx];
                        #pragma unroll
                        for (int xx = 0; xx < 14; ++xx)
                            acc1[xx] = fmaf(row[xx + kx], w, acc1[xx]);
                    }
                }
            }
            int gi = sub * 3 + m;
            #pragma unroll
            for (int j = 0; j < 7; ++j) {
                float v = fmaxf(fmaxf(acc0[2 * j], acc0[2 * j + 1]),
                                fmaxf(acc1[2 * j], acc1[2 * j + 1]));
                v = fmaxf(v, 0.f);
                // p1[img][y][x*6+ic], x = 7*hf+j
                sh[P1_S + gi * 1176 + i * 84 + (7 * hf + j) * 6 + c] = (short)f2bf(v);
            }
        }
        __syncthreads();
    }

    // ================= conv2 via MFMA: M=img(16,8 real), N=16 oc, K=5x32 =================
    {
        short8 Breg[5];
        #pragma unroll
        for (int s = 0; s < 5; ++s)
            Breg[s] = *(const short8*)(sh + BT_S + cn * 168 + s * 32 + 8 * g);

        for (int e = tid; e < 8 * 24; e += TH) {        // p2 k-pad zeros [400,424)
            int im = e / 24;
            sh[P2_S + im * 424 + 400 + (e - im * 24)] = 0;
        }

        for (int w = wid; w < 25; w += 4) {             // pool windows (i,jx)
            int i = w / 5, jx = w - 5 * i;
            floatx4 a00 = {0.f,0.f,0.f,0.f}, a01 = {0.f,0.f,0.f,0.f};
            floatx4 a10 = {0.f,0.f,0.f,0.f}, a11 = {0.f,0.f,0.f,0.f};
            #pragma unroll
            for (int s = 0; s < 5; ++s) {
                #pragma unroll
                for (int dy = 0; dy < 2; ++dy) {
                    #pragma unroll
                    for (int dx = 0; dx < 2; ++dx) {
                        int as = cn * 1176 + (2 * i + dy + s) * 84 + (2 * jx + dx) * 6 + 8 * g;
                        int ai = as >> 1;               // 4B-aligned (not 16B: x*6 granule)
                        short8 a;
                        int* av = (int*)&a;
                        av[0] = p1i[ai]; av[1] = p1i[ai + 1];
                        av[2] = p1i[ai + 2]; av[3] = p1i[ai + 3];
                        floatx4* acc = dy == 0 ? (dx == 0 ? &a00 : &a01)
                                               : (dx == 0 ? &a10 : &a11);
                        *acc = __builtin_amdgcn_mfma_f32_16x16x32_bf16(a, Breg[s], *acc, 0, 0, 0);
                    }
                }
            }
            if (g < 2) {                                 // C rows 0..7 = img
                #pragma unroll
                for (int rg = 0; rg < 4; ++rg) {
                    float v = fmaxf(fmaxf(a00[rg], a01[rg]), fmaxf(a10[rg], a11[rg]));
                    v = fmaxf(v, 0.f);
                    int im = 4 * g + rg;
                    sh[P2_S + im * 424 + cn * 25 + i * 5 + jx] = (short)f2bf(v);
                }
            }
        }
    }
    __syncthreads();

    // ================= fc1 via MFMA: K=400(13 steps), N=120(8 tiles) =================
    {
        for (int e = tid; e < 8 * 16; e += TH) {        // h1 pad zeros [120,136)
            int im = e >> 4;
            sh[H1_S + im * 136 + 120 + (e & 15)] = 0;
        }
        for (int nt = wid; nt < 8; nt += 4) {
            floatx4 acc = {0.f,0.f,0.f,0.f};
            int n = nt * 16 + cn;
            const float* wrow = fw1 + (size_t)(n < 120 ? n : 119) * 400;
            for (int ks = 0; ks < 13; ++ks) {
                int kb = ks * 32 + 8 * g;
                short8 b = load_bf8_clamped(wrow, kb, 400);
                short8 a = *(const short8*)(sh + P2_S + cn * 424 + kb);
                acc = __builtin_amdgcn_mfma_f32_16x16x32_bf16(a, b, acc, 0, 0, 0);
            }
            if (g < 2 && n < 120) {
                #pragma unroll
                for (int rg = 0; rg < 4; ++rg)
                    sh[H1_S + (4 * g + rg) * 136 + n] = (short)f2bf(fmaxf(acc[rg], 0.f));
            }
        }
    }
    __syncthreads();

    // ================= fc2 via MFMA: K=120(4 steps), N=84(6 tiles) =================
    {
        for (int e = tid; e < 8 * 20; e += TH) {        // h2 pad zeros [84,104)
            int im = e / 20;
            sh[H2_S + im * 104 + 84 + (e - im * 20)] = 0;
        }
        for (int nt = wid; nt < 6; nt += 4) {
            floatx4 acc = {0.f,0.f,0.f,0.f};
            int n = nt * 16 + cn;
            const float* wrow = fw2 + (size_t)(n < 84 ? n : 83) * 120;
            for (int ks = 0; ks < 4; ++ks) {
                int kb = ks * 32 + 8 * g;
                short8 b = load_bf8_clamped(wrow, kb, 120);
                short8 a = *(const short8*)(sh + H1_S + cn * 136 + kb);
                acc = __builtin_amdgcn_mfma_f32_16x16x32_bf16(a, b, acc, 0, 0, 0);
            }
            if (g < 2 && n < 84) {
                #pragma unroll
                for (int rg = 0; rg < 4; ++rg)
                    sh[H2_S + (4 * g + rg) * 104 + n] = (short)f2bf(fmaxf(acc[rg], 0.f));
            }
        }
    }
    __syncthreads();

    // ================= fc3 via MFMA: K=84(3 steps), N=10(1 tile) + bias =================
    if (wid == 0) {
        floatx4 acc = {0.f,0.f,0.f,0.f};
        int n = cn;
        const float* wrow = fc3w + (size_t)(n < 10 ? n : 9) * 84;
        for (int ks = 0; ks < 3; ++ks) {
            int kb = ks * 32 + 8 * g;
            short8 b = load_bf8_clamped(wrow, kb, 84);
            short8 a = *(const short8*)(sh + H2_S + cn * 104 + kb);
            acc = __builtin_amdgcn_mfma_f32_16x16x32_bf16(a, b, acc, 0, 0, 0);
        }
        if (g < 2 && n < 10) {
            float bias = fc3b[n];
            #pragma unroll
            for (int rg = 0; rg < 4; ++rg)
                sf[LOG_F + (4 * g + rg) * 12 + n] = acc[rg] + bias;
        }
    }
    __syncthreads();

    // ================= softmax, one thread per image =================
    if (tid < 8) {
        const float* lg = sf + LOG_F + tid * 12;
        float mx = lg[0];
        #pragma unroll
        for (int n = 1; n < 10; ++n) mx = fmaxf(mx, lg[n]);
        float e[10]; float sum = 0.f;
        #pragma unroll
        for (int n = 0; n < 10; ++n) { e[n] = expf(lg[n] - mx); sum += e[n]; }
        float inv = 1.f / sum;
        float* op = out + ((size_t)blk * 8 + tid) * 10;
        #pragma unroll
        for (int n = 0; n < 10; ++n) op[n] = e[n] * inv;
    }
}

extern "C" void kernel_launch(void* const* d_in, const int* in_sizes, int n_in,
                              void* d_out, int out_size, void* d_ws, size_t ws_size,
                              hipStream_t stream) {
    const float* x    = (const float*)d_in[0];
    const float* w1   = (const float*)d_in[1];
    const float* w2   = (const float*)d_in[2];
    const float* fw1  = (const float*)d_in[3];
    const float* fw2  = (const float*)d_in[4];
    const float* fc3w = (const float*)d_in[5];
    const float* fc3b = (const float*)d_in[6];
    float* outp = (float*)d_out;

    dim3 grid(16384 / 8), block(TH);
    hipLaunchKernelGGL(lenet_kernel, grid, block, 0, stream,
                       x, w1, w2, fw1, fw2, fc3w, fc3b, outp);
}

// Round 9
// 88.214 us; speedup vs baseline: 3.0568x; 1.1647x over previous
//
#include <hip/hip_runtime.h>
#include <hip/hip_fp16.h>
#include <math.h>

#define TH 256

typedef __attribute__((ext_vector_type(8))) short short8;
typedef __attribute__((ext_vector_type(4))) float floatx4;

// ---- LDS short-index constants (15808 shorts = 31616 B -> 5 blocks/CU) ----
#define P1_S   0        // 8 img * 1178 ([img][y*84 + x*6 + ic], bf16; odd-word stride: 16-bank spread)
#define X_S    9424     // fp16 x: up to 3 img * 1024 halfs (dead after conv1)
#define P2_S   9424     // aliases x: 8 img * 424 (k = oc*25+i*5+j, pad 400..423 = 0)
#define BT_S   12816    // 16 oc * 168 (w2 bf16: k = dy*32 + dx*6+ic, r>=30 -> 0)
#define H1_S   12816    // aliases BT after conv2: 8 img * 136 (pad 120..135 = 0)
#define H2_S   13904    // 8 img * 104 (pad 84..103 = 0)
#define LOG_F  7368     // float idx (shorts 14736..14928, inside dead BT)
#define W1B_U  7752     // uint idx: 150 broadcast half2 (shorts 15504..15804)
#define LDS_F  7904     // floats total = 31616 B

static __device__ __forceinline__ unsigned short f2bf(float x) {
    union { float f; unsigned u; } v; v.f = x;
    return (unsigned short)((v.u + 0x7FFFu + ((v.u >> 16) & 1u)) >> 16);   // RNE
}
static __device__ __forceinline__ __half2 uash2(unsigned u) {
    union { unsigned u; __half2 h; } v; v.u = u; return v.h;
}
// bf16-truncate-pack two fp32 words: out = [hi[31:16] : lo[31:16]]  (1x v_perm_b32)
static __device__ __forceinline__ unsigned bfpack(unsigned hi, unsigned lo) {
    return __builtin_amdgcn_perm(hi, lo, 0x07060302u);
}
// weights row[kb..kb+7] -> bf16 frag via truncation; per-quad clamp keeps loads in
// bounds at the K tail (matching A slots are zero-padded).
static __device__ __forceinline__ short8 load_bf8t(const float* row, int kb, int K) {
    int b0 = (kb + 4 <= K) ? kb : (K - 8);
    int b1 = (kb + 8 <= K) ? (kb + 4) : (K - 8);
    uint4 w0 = *(const uint4*)(row + b0);
    uint4 w1 = *(const uint4*)(row + b1);
    union { int4 i; short8 s; } r;
    r.i.x = (int)bfpack(w0.y, w0.x);
    r.i.y = (int)bfpack(w0.w, w0.z);
    r.i.z = (int)bfpack(w1.y, w1.x);
    r.i.w = (int)bfpack(w1.w, w1.z);
    return r.s;
}

// NOTE: no min-waves arg (round 3: (320,5) capped VGPR=48 -> scratch spill storm).
__global__ __launch_bounds__(TH) void lenet_kernel(
    const float* __restrict__ x,
    const float* __restrict__ w1,
    const float* __restrict__ w2g,
    const float* __restrict__ fw1,
    const float* __restrict__ fw2,
    const float* __restrict__ fc3w,
    const float* __restrict__ fc3b,
    float* __restrict__ out)
{
    __shared__ __align__(16) float sf[LDS_F];
    short* sh = (short*)sf;
    unsigned* su = (unsigned*)sf;
    const int* p1i = (const int*)sf;

    const int tid  = threadIdx.x;
    const int blk  = blockIdx.x;
    const int lane = tid & 63;
    const int wid  = tid >> 6;
    const int g    = lane >> 4;     // k-group selector of MFMA frags
    const int cn   = lane & 15;     // row(A)/col(B) selector
    const int pr   = cn & 7;        // clamped A-row (rows 8..15 duplicate 0..7; C rows 8..15 discarded)

    // ================= conv1 (packed fp16 VALU), 3 x-substages =================
    for (int sub = 0; sub < 3; ++sub) {
        const int nimg = (sub < 2) ? 3 : 2;
        const float4* xg = (const float4*)(x + ((size_t)blk * 8 + sub * 3) * 1024);
        for (int e = tid; e < nimg * 256; e += TH) {
            float4 v = xg[e];
            int off = X_S + e * 4;                    // [img][1024] halfs
            *(__half2*)(sh + off)     = __floats2half2_rn(v.x, v.y);
            *(__half2*)(sh + off + 2) = __floats2half2_rn(v.z, v.w);
        }
        if (sub == 0) {
            for (int e = tid; e < 150; e += TH) {
                __half h = __float2half(w1[e]);
                ((__half2*)(su + W1B_U))[e] = __half2half2(h);
            }
            // Bt[oc][dy*32 + r], r = dx*6+ic (<30), zero-pad r=30,31
            for (int e = tid; e < 2560; e += TH) {
                int oc = e / 160, kk = e - oc * 160;
                int s = kk >> 5, r = kk & 31;
                float v = 0.f;
                if (r < 30) v = w2g[oc * 150 + (r % 6) * 25 + s * 5 + (r / 6)];
                sh[BT_S + oc * 168 + kk] = (short)f2bf(v);
            }
        }
        __syncthreads();

        const int ntask = nimg * 168;
        for (int t = tid; t < ntask; t += TH) {
            int m = t / 168, r = t - m * 168;
            int c = r % 6, q = r / 6;
            int i = q >> 1, hf = q & 1;
            const __half2* wb = (const __half2*)(su + W1B_U) + c * 25;
            const int xbase = X_S + m * 1024 + hf * 14;

            __half2 acc0[7], acc1[7];
            #pragma unroll
            for (int j = 0; j < 7; ++j) { acc0[j] = uash2(0u); acc1[j] = uash2(0u); }
            __half2 wprev[5];
            #pragma unroll
            for (int tt = 0; tt < 6; ++tt) {
                unsigned u[9];
                const unsigned* rp = (const unsigned*)(sh + xbase + (2 * i + tt) * 32);
                #pragma unroll
                for (int qq = 0; qq < 9; ++qq) u[qq] = rp[qq];
                __half2 p0[9], p1[8];
                #pragma unroll
                for (int qq = 0; qq < 9; ++qq) p0[qq] = uash2(u[qq]);
                #pragma unroll
                for (int qq = 0; qq < 8; ++qq)
                    p1[qq] = uash2(__builtin_amdgcn_perm(u[qq + 1], u[qq], 0x05040302u));

                if (tt < 5) {
                    __half2 wc[5];
                    #pragma unroll
                    for (int kx = 0; kx < 5; ++kx) wc[kx] = wb[tt * 5 + kx];
                    #pragma unroll
                    for (int j = 0; j < 7; ++j) {
                        acc0[j] = __hfma2(p0[j],     wc[0], acc0[j]);
                        acc0[j] = __hfma2(p1[j],     wc[1], acc0[j]);
                        acc0[j] = __hfma2(p0[j + 1], wc[2], acc0[j]);
                        acc0[j] = __hfma2(p1[j + 1], wc[3], acc0[j]);
                        acc0[j] = __hfma2(p0[j + 2], wc[4], acc0[j]);
                    }
                    if (tt >= 1) {
                        #pragma unroll
                        for (int j = 0; j < 7; ++j) {
                            acc1[j] = __hfma2(p0[j],     wprev[0], acc1[j]);
                            acc1[j] = __hfma2(p1[j],     wprev[1], acc1[j]);
                            acc1[j] = __hfma2(p0[j + 1], wprev[2], acc1[j]);
                            acc1[j] = __hfma2(p1[j + 1], wprev[3], acc1[j]);
                            acc1[j] = __hfma2(p0[j + 2], wprev[4], acc1[j]);
                        }
                    }
                    #pragma unroll
                    for (int kx = 0; kx < 5; ++kx) wprev[kx] = wc[kx];
                } else {    // tt == 5: acc1 only, with w row 4 (in wprev)
                    #pragma unroll
                    for (int j = 0; j < 7; ++j) {
                        acc1[j] = __hfma2(p0[j],     wprev[0], acc1[j]);
                        acc1[j] = __hfma2(p1[j],     wprev[1], acc1[j]);
                        acc1[j] = __hfma2(p0[j + 1], wprev[2], acc1[j]);
                        acc1[j] = __hfma2(p1[j + 1], wprev[3], acc1[j]);
                        acc1[j] = __hfma2(p0[j + 2], wprev[4], acc1[j]);
                    }
                }
            }
            int gi = sub * 3 + m;
            short* dst = sh + P1_S + gi * 1178 + i * 84 + hf * 42 + c;
            #pragma unroll
            for (int j = 0; j < 7; ++j) {
                // fp32 epilogue max (ROCm 7.2 lacks __hmax2/__hmax overloads)
                float a0l = __half2float(__low2half(acc0[j]));
                float a0h = __half2float(__high2half(acc0[j]));
                float a1l = __half2float(__low2half(acc1[j]));
                float a1h = __half2float(__high2half(acc1[j]));
                float v = fmaxf(fmaxf(fmaxf(a0l, a0h), fmaxf(a1l, a1h)), 0.f);
                dst[j * 6] = (short)f2bf(v);
            }
        }
        __syncthreads();
    }

    // ================= conv2 via MFMA: M=img(16,8 real), N=16 oc, K=5x32 =================
    {
        short8 Breg[5];
        #pragma unroll
        for (int s = 0; s < 5; ++s)
            Breg[s] = *(const short8*)(sh + BT_S + cn * 168 + s * 32 + 8 * g);

        for (int e = tid; e < 8 * 24; e += TH) {        // p2 k-pad zeros [400,424)
            int im = e / 24;
            sh[P2_S + im * 424 + 400 + (e - im * 24)] = 0;
        }

        for (int w = wid; w < 25; w += 4) {             // pool windows (i,jx)
            int i = w / 5, jx = w - 5 * i;
            floatx4 a00 = {0.f,0.f,0.f,0.f}, a01 = {0.f,0.f,0.f,0.f};
            floatx4 a10 = {0.f,0.f,0.f,0.f}, a11 = {0.f,0.f,0.f,0.f};
            #pragma unroll
            for (int s = 0; s < 5; ++s) {
                #pragma unroll
                for (int dy = 0; dy < 2; ++dy) {
                    #pragma unroll
                    for (int dx = 0; dx < 2; ++dx) {
                        int as = pr * 1178 + (2 * i + dy + s) * 84 + (2 * jx + dx) * 6 + 8 * g;
                        int ai = as >> 1;               // 4B-aligned
                        union { int4 i4; short8 s8; } a;
                        a.i4.x = p1i[ai];     a.i4.y = p1i[ai + 1];
                        a.i4.z = p1i[ai + 2]; a.i4.w = p1i[ai + 3];
                        floatx4* acc = dy == 0 ? (dx == 0 ? &a00 : &a01)
                                               : (dx == 0 ? &a10 : &a11);
                        *acc = __builtin_amdgcn_mfma_f32_16x16x32_bf16(a.s8, Breg[s], *acc, 0, 0, 0);
                    }
                }
            }
            if (g < 2) {                                 // C rows 0..7 = real imgs
                #pragma unroll
                for (int rg = 0; rg < 4; ++rg) {
                    float v = fmaxf(fmaxf(a00[rg], a01[rg]), fmaxf(a10[rg], a11[rg]));
                    v = fmaxf(v, 0.f);
                    int im = 4 * g + rg;
                    sh[P2_S + im * 424 + cn * 25 + i * 5 + jx] = (short)f2bf(v);
                }
            }
        }
    }
    __syncthreads();

    // ================= fc1 via MFMA: K=400(13 steps), N=120(8 tiles) =================
    {
        for (int e = tid; e < 8 * 16; e += TH) {        // h1 pad zeros [120,136)
            int im = e >> 4;
            sh[H1_S + im * 136 + 120 + (e & 15)] = 0;
        }
        for (int nt = wid; nt < 8; nt += 4) {
            floatx4 acc = {0.f,0.f,0.f,0.f};
            int n = nt * 16 + cn;
            const float* wrow = fw1 + (size_t)(n < 120 ? n : 119) * 400;
            for (int ks = 0; ks < 13; ++ks) {
                int kb = ks * 32 + 8 * g;
                short8 b = load_bf8t(wrow, kb, 400);
                short8 a = *(const short8*)(sh + P2_S + pr * 424 + kb);
                acc = __builtin_amdgcn_mfma_f32_16x16x32_bf16(a, b, acc, 0, 0, 0);
            }
            if (g < 2 && n < 120) {
                #pragma unroll
                for (int rg = 0; rg < 4; ++rg)
                    sh[H1_S + (4 * g + rg) * 136 + n] = (short)f2bf(fmaxf(acc[rg], 0.f));
            }
        }
    }
    __syncthreads();

    // ================= fc2 via MFMA: K=120(4 steps), N=84(6 tiles) =================
    {
        for (int e = tid; e < 8 * 20; e += TH) {        // h2 pad zeros [84,104)
            int im = e / 20;
            sh[H2_S + im * 104 + 84 + (e - im * 20)] = 0;
        }
        for (int nt = wid; nt < 6; nt += 4) {
            floatx4 acc = {0.f,0.f,0.f,0.f};
            int n = nt * 16 + cn;
            const float* wrow = fw2 + (size_t)(n < 84 ? n : 83) * 120;
            for (int ks = 0; ks < 4; ++ks) {
                int kb = ks * 32 + 8 * g;
                short8 b = load_bf8t(wrow, kb, 120);
                short8 a = *(const short8*)(sh + H1_S + pr * 136 + kb);
                acc = __builtin_amdgcn_mfma_f32_16x16x32_bf16(a, b, acc, 0, 0, 0);
            }
            if (g < 2 && n < 84) {
                #pragma unroll
                for (int rg = 0; rg < 4; ++rg)
                    sh[H2_S + (4 * g + rg) * 104 + n] = (short)f2bf(fmaxf(acc[rg], 0.f));
            }
        }
    }
    __syncthreads();

    // ================= fc3 via MFMA: K=84(3 steps), N=10 + bias =================
    if (wid == 0) {
        floatx4 acc = {0.f,0.f,0.f,0.f};
        int n = cn;
        const float* wrow = fc3w + (size_t)(n < 10 ? n : 9) * 84;
        for (int ks = 0; ks < 3; ++ks) {
            int kb = ks * 32 + 8 * g;
            short8 b = load_bf8t(wrow, kb, 84);
            short8 a = *(const short8*)(sh + H2_S + pr * 104 + kb);
            acc = __builtin_amdgcn_mfma_f32_16x16x32_bf16(a, b, acc, 0, 0, 0);
        }
        if (g < 2 && n < 10) {
            float bias = fc3b[n];
            #pragma unroll
            for (int rg = 0; rg < 4; ++rg)
                sf[LOG_F + (4 * g + rg) * 12 + n] = acc[rg] + bias;
        }
    }
    __syncthreads();

    // ================= softmax, one thread per image =================
    if (tid < 8) {
        const float* lg = sf + LOG_F + tid * 12;
        float mx = lg[0];
        #pragma unroll
        for (int n = 1; n < 10; ++n) mx = fmaxf(mx, lg[n]);
        float e[10]; float sum = 0.f;
        #pragma unroll
        for (int n = 0; n < 10; ++n) { e[n] = expf(lg[n] - mx); sum += e[n]; }
        float inv = 1.f / sum;
        float* op = out + ((size_t)blk * 8 + tid) * 10;
        #pragma unroll
        for (int n = 0; n < 10; ++n) op[n] = e[n] * inv;
    }
}

extern "C" void kernel_launch(void* const* d_in, const int* in_sizes, int n_in,
                              void* d_out, int out_size, void* d_ws, size_t ws_size,
                              hipStream_t stream) {
    const float* x    = (const float*)d_in[0];
    const float* w1   = (const float*)d_in[1];
    const float* w2   = (const float*)d_in[2];
    const float* fw1  = (const float*)d_in[3];
    const float* fw2  = (const float*)d_in[4];
    const float* fc3w = (const float*)d_in[5];
    const float* fc3b = (const float*)d_in[6];
    float* outp = (float*)d_out;

    dim3 grid(16384 / 8), block(TH);
    hipLaunchKernelGGL(lenet_kernel, grid, block, 0, stream,
                       x, w1, w2, fw1, fw2, fc3w, fc3b, outp);
}

// Round 10
// 84.563 us; speedup vs baseline: 3.1888x; 1.0432x over previous
//
#include <hip/hip_runtime.h>
#include <hip/hip_fp16.h>
#include <math.h>

#define TH 256

typedef __attribute__((ext_vector_type(8))) short short8;
typedef __attribute__((ext_vector_type(4))) float floatx4;

// ---- LDS short-index constants (15808 shorts = 31616 B -> 5 blocks/CU) ----
#define P1_S   0        // 8 img * 1178 ([img][y*84 + x*6 + ic], bf16; odd-word stride: 16-bank spread)
#define X_S    9424     // fp16 x: up to 3 img * 1090 halfs, row stride 34 (odd word -> bank spread)
#define P2_S   9424     // aliases x: 8 img * 424 (k = oc*25+i*5+j, pad 400..423 = 0)
#define BT_S   12816    // 16 oc * 168 (w2 bf16: k = dy*32 + dx*6+ic, r>=30 -> 0)
#define H1_S   12816    // aliases BT after conv2: 8 img * 136 (pad 120..135 = 0)
#define H2_S   13904    // 8 img * 104 (pad 84..103 = 0)
#define LOG_F  7368     // float idx (shorts 14736..14928, inside dead BT)
#define W1B_U  7752     // uint idx: 150 broadcast half2 (shorts 15504..15804)
#define LDS_F  7904     // floats total = 31616 B

static __device__ __forceinline__ unsigned short f2bf(float x) {
    union { float f; unsigned u; } v; v.f = x;
    return (unsigned short)((v.u + 0x7FFFu + ((v.u >> 16) & 1u)) >> 16);   // RNE
}
static __device__ __forceinline__ __half2 uash2(unsigned u) {
    union { unsigned u; __half2 h; } v; v.u = u; return v.h;
}
// bf16-truncate-pack two fp32 words: out = [hi[31:16] : lo[31:16]]  (1x v_perm_b32)
static __device__ __forceinline__ unsigned bfpack(unsigned hi, unsigned lo) {
    return __builtin_amdgcn_perm(hi, lo, 0x07060302u);
}
// weights row[kb..kb+7] -> bf16 frag via truncation; per-quad clamp keeps loads in
// bounds at the K tail (matching A slots are zero-padded).
static __device__ __forceinline__ short8 load_bf8t(const float* row, int kb, int K) {
    int b0 = (kb + 4 <= K) ? kb : (K - 8);
    int b1 = (kb + 8 <= K) ? (kb + 4) : (K - 8);
    uint4 w0 = *(const uint4*)(row + b0);
    uint4 w1 = *(const uint4*)(row + b1);
    union { int4 i; short8 s; } r;
    r.i.x = (int)bfpack(w0.y, w0.x);
    r.i.y = (int)bfpack(w0.w, w0.z);
    r.i.z = (int)bfpack(w1.y, w1.x);
    r.i.w = (int)bfpack(w1.w, w1.z);
    return r.s;
}

// NOTE: no min-waves arg (round 3: (320,5) capped VGPR=48 -> scratch spill storm).
__global__ __launch_bounds__(TH) void lenet_kernel(
    const float* __restrict__ x,
    const float* __restrict__ w1,
    const float* __restrict__ w2g,
    const float* __restrict__ fw1,
    const float* __restrict__ fw2,
    const float* __restrict__ fc3w,
    const float* __restrict__ fc3b,
    float* __restrict__ out)
{
    __shared__ __align__(16) float sf[LDS_F];
    short* sh = (short*)sf;
    unsigned* su = (unsigned*)sf;
    const int* p1i = (const int*)sf;

    const int tid  = threadIdx.x;
    const int blk  = blockIdx.x;
    const int lane = tid & 63;
    const int wid  = tid >> 6;
    const int g    = lane >> 4;     // k-group selector of MFMA frags
    const int cn   = lane & 15;     // row(A)/col(B) selector
    const int pr   = cn & 7;        // clamped A-row (rows 8..15 duplicate 0..7; C rows 8..15 discarded)

    // ================= conv1 (packed fp16 VALU), 3 x-substages =================
    for (int sub = 0; sub < 3; ++sub) {
        const int nimg = (sub < 2) ? 3 : 2;
        const float4* xg = (const float4*)(x + ((size_t)blk * 8 + sub * 3) * 1024);
        for (int e = tid; e < nimg * 256; e += TH) {
            float4 v = xg[e];
            int m = e >> 8, rem = e & 255;
            int y = rem >> 3, k4 = rem & 7;
            // row stride 34 halfs (17 words, odd) + image stride 1090 (545 words, odd):
            // bank = (m*545 + hf*7 + row*17) % 32 varies with row -> conflict-free conv1 reads.
            int off = X_S + m * 1090 + y * 34 + k4 * 4;
            *(__half2*)(sh + off)     = __floats2half2_rn(v.x, v.y);
            *(__half2*)(sh + off + 2) = __floats2half2_rn(v.z, v.w);
        }
        if (sub == 0) {
            for (int e = tid; e < 150; e += TH) {
                __half h = __float2half(w1[e]);
                ((__half2*)(su + W1B_U))[e] = __half2half2(h);
            }
            // Bt[oc][dy*32 + r], r = dx*6+ic (<30), zero-pad r=30,31
            for (int e = tid; e < 2560; e += TH) {
                int oc = e / 160, kk = e - oc * 160;
                int s = kk >> 5, r = kk & 31;
                float v = 0.f;
                if (r < 30) v = w2g[oc * 150 + (r % 6) * 25 + s * 5 + (r / 6)];
                sh[BT_S + oc * 168 + kk] = (short)f2bf(v);
            }
        }
        __syncthreads();

        const int ntask = nimg * 168;
        for (int t = tid; t < ntask; t += TH) {
            int m = t / 168, r = t - m * 168;
            int c = r % 6, q = r / 6;
            int i = q >> 1, hf = q & 1;
            const __half2* wb = (const __half2*)(su + W1B_U) + c * 25;
            const int xbase = X_S + m * 1090 + hf * 14;

            __half2 acc0[7], acc1[7];
            #pragma unroll
            for (int j = 0; j < 7; ++j) { acc0[j] = uash2(0u); acc1[j] = uash2(0u); }
            __half2 wprev[5];
            #pragma unroll
            for (int tt = 0; tt < 6; ++tt) {
                unsigned u[9];
                const unsigned* rp = (const unsigned*)(sh + xbase + (2 * i + tt) * 34);
                #pragma unroll
                for (int qq = 0; qq < 9; ++qq) u[qq] = rp[qq];
                __half2 p0[9], p1[8];
                #pragma unroll
                for (int qq = 0; qq < 9; ++qq) p0[qq] = uash2(u[qq]);
                #pragma unroll
                for (int qq = 0; qq < 8; ++qq)
                    p1[qq] = uash2(__builtin_amdgcn_perm(u[qq + 1], u[qq], 0x05040302u));

                if (tt < 5) {
                    __half2 wc[5];
                    #pragma unroll
                    for (int kx = 0; kx < 5; ++kx) wc[kx] = wb[tt * 5 + kx];
                    #pragma unroll
                    for (int j = 0; j < 7; ++j) {
                        acc0[j] = __hfma2(p0[j],     wc[0], acc0[j]);
                        acc0[j] = __hfma2(p1[j],     wc[1], acc0[j]);
                        acc0[j] = __hfma2(p0[j + 1], wc[2], acc0[j]);
                        acc0[j] = __hfma2(p1[j + 1], wc[3], acc0[j]);
                        acc0[j] = __hfma2(p0[j + 2], wc[4], acc0[j]);
                    }
                    if (tt >= 1) {
                        #pragma unroll
                        for (int j = 0; j < 7; ++j) {
                            acc1[j] = __hfma2(p0[j],     wprev[0], acc1[j]);
                            acc1[j] = __hfma2(p1[j],     wprev[1], acc1[j]);
                            acc1[j] = __hfma2(p0[j + 1], wprev[2], acc1[j]);
                            acc1[j] = __hfma2(p1[j + 1], wprev[3], acc1[j]);
                            acc1[j] = __hfma2(p0[j + 2], wprev[4], acc1[j]);
                        }
                    }
                    #pragma unroll
                    for (int kx = 0; kx < 5; ++kx) wprev[kx] = wc[kx];
                } else {    // tt == 5: acc1 only, with w row 4 (in wprev)
                    #pragma unroll
                    for (int j = 0; j < 7; ++j) {
                        acc1[j] = __hfma2(p0[j],     wprev[0], acc1[j]);
                        acc1[j] = __hfma2(p1[j],     wprev[1], acc1[j]);
                        acc1[j] = __hfma2(p0[j + 1], wprev[2], acc1[j]);
                        acc1[j] = __hfma2(p1[j + 1], wprev[3], acc1[j]);
                        acc1[j] = __hfma2(p0[j + 2], wprev[4], acc1[j]);
                    }
                }
            }
            int gi = sub * 3 + m;
            short* dst = sh + P1_S + gi * 1178 + i * 84 + hf * 42 + c;
            #pragma unroll
            for (int j = 0; j < 7; ++j) {
                // fp32 epilogue max (ROCm 7.2 lacks __hmax2/__hmax overloads)
                float a0l = __half2float(__low2half(acc0[j]));
                float a0h = __half2float(__high2half(acc0[j]));
                float a1l = __half2float(__low2half(acc1[j]));
                float a1h = __half2float(__high2half(acc1[j]));
                float v = fmaxf(fmaxf(fmaxf(a0l, a0h), fmaxf(a1l, a1h)), 0.f);
                dst[j * 6] = (short)f2bf(v);
            }
        }
        __syncthreads();
    }

    // ================= conv2 via MFMA: M=img(16,8 real), N=16 oc, K=5x32 =================
    {
        short8 Breg[5];
        #pragma unroll
        for (int s = 0; s < 5; ++s)
            Breg[s] = *(const short8*)(sh + BT_S + cn * 168 + s * 32 + 8 * g);

        for (int e = tid; e < 8 * 24; e += TH) {        // p2 k-pad zeros [400,424)
            int im = e / 24;
            sh[P2_S + im * 424 + 400 + (e - im * 24)] = 0;
        }

        for (int w = wid; w < 25; w += 4) {             // pool windows (i,jx)
            int i = w / 5, jx = w - 5 * i;
            floatx4 a00 = {0.f,0.f,0.f,0.f}, a01 = {0.f,0.f,0.f,0.f};
            floatx4 a10 = {0.f,0.f,0.f,0.f}, a11 = {0.f,0.f,0.f,0.f};
            #pragma unroll
            for (int s = 0; s < 5; ++s) {
                #pragma unroll
                for (int dy = 0; dy < 2; ++dy) {
                    #pragma unroll
                    for (int dx = 0; dx < 2; ++dx) {
                        int as = pr * 1178 + (2 * i + dy + s) * 84 + (2 * jx + dx) * 6 + 8 * g;
                        int ai = as >> 1;               // 4B-aligned
                        union { int4 i4; short8 s8; } a;
                        a.i4.x = p1i[ai];     a.i4.y = p1i[ai + 1];
                        a.i4.z = p1i[ai + 2]; a.i4.w = p1i[ai + 3];
                        floatx4* acc = dy == 0 ? (dx == 0 ? &a00 : &a01)
                                               : (dx == 0 ? &a10 : &a11);
                        *acc = __builtin_amdgcn_mfma_f32_16x16x32_bf16(a.s8, Breg[s], *acc, 0, 0, 0);
                    }
                }
            }
            if (g < 2) {                                 // C rows 0..7 = real imgs
                #pragma unroll
                for (int rg = 0; rg < 4; ++rg) {
                    float v = fmaxf(fmaxf(a00[rg], a01[rg]), fmaxf(a10[rg], a11[rg]));
                    v = fmaxf(v, 0.f);
                    int im = 4 * g + rg;
                    sh[P2_S + im * 424 + cn * 25 + i * 5 + jx] = (short)f2bf(v);
                }
            }
        }
    }
    __syncthreads();

    // ================= fc1 via MFMA: K=400(13 steps), N=120(8 tiles) =================
    {
        for (int e = tid; e < 8 * 16; e += TH) {        // h1 pad zeros [120,136)
            int im = e >> 4;
            sh[H1_S + im * 136 + 120 + (e & 15)] = 0;
        }
        for (int nt = wid; nt < 8; nt += 4) {
            floatx4 acc = {0.f,0.f,0.f,0.f};
            int n = nt * 16 + cn;
            const float* wrow = fw1 + (size_t)(n < 120 ? n : 119) * 400;
            for (int ks = 0; ks < 13; ++ks) {
                int kb = ks * 32 + 8 * g;
                short8 b = load_bf8t(wrow, kb, 400);
                short8 a = *(const short8*)(sh + P2_S + pr * 424 + kb);
                acc = __builtin_amdgcn_mfma_f32_16x16x32_bf16(a, b, acc, 0, 0, 0);
            }
            if (g < 2 && n < 120) {
                #pragma unroll
                for (int rg = 0; rg < 4; ++rg)
                    sh[H1_S + (4 * g + rg) * 136 + n] = (short)f2bf(fmaxf(acc[rg], 0.f));
            }
        }
    }
    __syncthreads();

    // ================= fc2 via MFMA: K=120(4 steps), N=84(6 tiles) =================
    {
        for (int e = tid; e < 8 * 20; e += TH) {        // h2 pad zeros [84,104)
            int im = e / 20;
            sh[H2_S + im * 104 + 84 + (e - im * 20)] = 0;
        }
        for (int nt = wid; nt < 6; nt += 4) {
            floatx4 acc = {0.f,0.f,0.f,0.f};
            int n = nt * 16 + cn;
            const float* wrow = fw2 + (size_t)(n < 84 ? n : 83) * 120;
            for (int ks = 0; ks < 4; ++ks) {
                int kb = ks * 32 + 8 * g;
                short8 b = load_bf8t(wrow, kb, 120);
                short8 a = *(const short8*)(sh + H1_S + pr * 136 + kb);
                acc = __builtin_amdgcn_mfma_f32_16x16x32_bf16(a, b, acc, 0, 0, 0);
            }
            if (g < 2 && n < 84) {
                #pragma unroll
                for (int rg = 0; rg < 4; ++rg)
                    sh[H2_S + (4 * g + rg) * 104 + n] = (short)f2bf(fmaxf(acc[rg], 0.f));
            }
        }
    }
    __syncthreads();

    // ================= fc3 via MFMA: K=84(3 steps), N=10 + bias =================
    if (wid == 0) {
        floatx4 acc = {0.f,0.f,0.f,0.f};
        int n = cn;
        const float* wrow = fc3w + (size_t)(n < 10 ? n : 9) * 84;
        for (int ks = 0; ks < 3; ++ks) {
            int kb = ks * 32 + 8 * g;
            short8 b = load_bf8t(wrow, kb, 84);
            short8 a = *(const short8*)(sh + H2_S + pr * 104 + kb);
            acc = __builtin_amdgcn_mfma_f32_16x16x32_bf16(a, b, acc, 0, 0, 0);
        }
        if (g < 2 && n < 10) {
            float bias = fc3b[n];
            #pragma unroll
            for (int rg = 0; rg < 4; ++rg)
                sf[LOG_F + (4 * g + rg) * 12 + n] = acc[rg] + bias;
        }
    }
    __syncthreads();

    // ================= softmax, one thread per image =================
    if (tid < 8) {
        const float* lg = sf + LOG_F + tid * 12;
        float mx = lg[0];
        #pragma unroll
        for (int n = 1; n < 10; ++n) mx = fmaxf(mx, lg[n]);
        float e[10]; float sum = 0.f;
        #pragma unroll
        for (int n = 0; n < 10; ++n) { e[n] = expf(lg[n] - mx); sum += e[n]; }
        float inv = 1.f / sum;
        float* op = out + ((size_t)blk * 8 + tid) * 10;
        #pragma unroll
        for (int n = 0; n < 10; ++n) op[n] = e[n] * inv;
    }
}

extern "C" void kernel_launch(void* const* d_in, const int* in_sizes, int n_in,
                              void* d_out, int out_size, void* d_ws, size_t ws_size,
                              hipStream_t stream) {
    const float* x    = (const float*)d_in[0];
    const float* w1   = (const float*)d_in[1];
    const float* w2   = (const float*)d_in[2];
    const float* fw1  = (const float*)d_in[3];
    const float* fw2  = (const float*)d_in[4];
    const float* fc3w = (const float*)d_in[5];
    const float* fc3b = (const float*)d_in[6];
    float* outp = (float*)d_out;

    dim3 grid(16384 / 8), block(TH);
    hipLaunchKernelGGL(lenet_kernel, grid, block, 0, stream,
                       x, w1, w2, fw1, fw2, fc3w, fc3b, outp);
}

// Round 11
// 82.236 us; speedup vs baseline: 3.2790x; 1.0283x over previous
//
#include <hip/hip_runtime.h>
#include <hip/hip_fp16.h>
#include <math.h>

#define TH 256

typedef __attribute__((ext_vector_type(8))) short short8;
typedef __attribute__((ext_vector_type(4))) float floatx4;

// ---- LDS short-index constants (15808 shorts = 31616 B -> 5 blocks/CU) ----
#define P1_S   0        // 8 img * 1178 ([img][y*84 + x*6 + ic], bf16; odd-word stride)
#define X_S    9424     // fp16 x: up to 3 img * 1090 halfs, row stride 34 (odd word)
#define P2_S   9424     // aliases x: 8 img * 424 (k = oc*25+i*5+j, pad 400..423 = 0)
#define BT_S   12816    // 16 oc * 168 (w2 bf16: k = ky*32 + dx*6+ic, r>=30 -> 0)
#define H1_S   12816    // aliases BT after conv2: 8 img * 136 (pad 120..135 = 0)
#define H2_S   13904    // 8 img * 104 (pad 84..103 = 0)
#define LOG_F  7368     // float idx (shorts 14736..14928, inside dead BT)
#define W1B_U  7752     // uint idx: 150 broadcast half2 (shorts 15504..15804)
#define LDS_F  7904     // floats total = 31616 B

static __device__ __forceinline__ unsigned short f2bf(float x) {
    union { float f; unsigned u; } v; v.f = x;
    return (unsigned short)((v.u + 0x7FFFu + ((v.u >> 16) & 1u)) >> 16);   // RNE
}
static __device__ __forceinline__ __half2 uash2(unsigned u) {
    union { unsigned u; __half2 h; } v; v.u = u; return v.h;
}
// bf16-truncate-pack two fp32 words: out = [hi[31:16] : lo[31:16]]  (1x v_perm_b32)
static __device__ __forceinline__ unsigned bfpack(unsigned hi, unsigned lo) {
    return __builtin_amdgcn_perm(hi, lo, 0x07060302u);
}
// weights row[kb..kb+7] -> bf16 frag via truncation; per-quad clamp keeps loads in
// bounds at the K tail (matching A slots are zero-padded).
static __device__ __forceinline__ short8 load_bf8t(const float* row, int kb, int K) {
    int b0 = (kb + 4 <= K) ? kb : (K - 8);
    int b1 = (kb + 8 <= K) ? (kb + 4) : (K - 8);
    uint4 w0 = *(const uint4*)(row + b0);
    uint4 w1 = *(const uint4*)(row + b1);
    union { int4 i; short8 s; } r;
    r.i.x = (int)bfpack(w0.y, w0.x);
    r.i.y = (int)bfpack(w0.w, w0.z);
    r.i.z = (int)bfpack(w1.y, w1.x);
    r.i.w = (int)bfpack(w1.w, w1.z);
    return r.s;
}

// NOTE: no min-waves arg (round 3: (320,5) capped VGPR=48 -> scratch spill storm).
__global__ __launch_bounds__(TH) void lenet_kernel(
    const float* __restrict__ x,
    const float* __restrict__ w1,
    const float* __restrict__ w2g,
    const float* __restrict__ fw1,
    const float* __restrict__ fw2,
    const float* __restrict__ fc3w,
    const float* __restrict__ fc3b,
    float* __restrict__ out)
{
    __shared__ __align__(16) float sf[LDS_F];
    short* sh = (short*)sf;
    unsigned* su = (unsigned*)sf;
    const int* p1i = (const int*)sf;

    const int tid  = threadIdx.x;
    const int blk  = blockIdx.x;
    const int lane = tid & 63;
    const int wid  = tid >> 6;
    const int g    = lane >> 4;     // k-group selector of MFMA frags
    const int cn   = lane & 15;     // row(A)/col(B) selector
    const int pr   = cn & 7;        // img row (conv2: rows 8..15 = dy=1 of imgs 0..7)
    const int dyr  = cn >> 3;       // conv2 pool-row packed into M

    // ================= conv1 (packed fp16 VALU), 3 substages, x prefetched to regs =================
    float4 xreg[3];
    {
        const float4* xg0 = (const float4*)(x + (size_t)blk * 8 * 1024);
        #pragma unroll
        for (int j = 0; j < 3; ++j) { int e = tid + j * TH; if (e < 768) xreg[j] = xg0[e]; }
    }
    for (int sub = 0; sub < 3; ++sub) {
        const int nimg = (sub < 2) ? 3 : 2;
        if (sub) __syncthreads();               // prev compute done -> x region reusable
        #pragma unroll
        for (int j = 0; j < 3; ++j) {
            int e = tid + j * TH;
            if (e < nimg * 256) {
                float4 v = xreg[j];
                int m = e >> 8, rem = e & 255;
                int y = rem >> 3, k4 = rem & 7;
                // row stride 34 halfs (17 words, odd): conflict-free conv1 reads (round 10)
                int off = X_S + m * 1090 + y * 34 + k4 * 4;
                *(__half2*)(sh + off)     = __floats2half2_rn(v.x, v.y);
                *(__half2*)(sh + off + 2) = __floats2half2_rn(v.z, v.w);
            }
        }
        if (sub == 0) {
            for (int e = tid; e < 150; e += TH) {
                __half h = __float2half(w1[e]);
                ((__half2*)(su + W1B_U))[e] = __half2half2(h);
            }
            // Bt[oc][ky*32 + r], r = dx*6+ic (<30), zero-pad r=30,31
            for (int e = tid; e < 2560; e += TH) {
                int oc = e / 160, kk = e - oc * 160;
                int s = kk >> 5, r = kk & 31;
                float v = 0.f;
                if (r < 30) v = w2g[oc * 150 + (r % 6) * 25 + s * 5 + (r / 6)];
                sh[BT_S + oc * 168 + kk] = (short)f2bf(v);
            }
        }
        __syncthreads();

        // T14: issue next substage's global loads now; latency hides under compute
        if (sub < 2) {
            const int nimgn = (sub == 0) ? 3 : 2;
            const float4* xgn = (const float4*)(x + ((size_t)blk * 8 + (sub + 1) * 3) * 1024);
            #pragma unroll
            for (int j = 0; j < 3; ++j) { int e = tid + j * TH; if (e < nimgn * 256) xreg[j] = xgn[e]; }
        }

        const int ntask = nimg * 168;
        for (int t = tid; t < ntask; t += TH) {
            int m = t / 168, r = t - m * 168;
            int c = r % 6, q = r / 6;
            int i = q >> 1, hf = q & 1;
            const __half2* wb = (const __half2*)(su + W1B_U) + c * 25;
            const int xbase = X_S + m * 1090 + hf * 14;

            __half2 acc0[7], acc1[7];
            #pragma unroll
            for (int j = 0; j < 7; ++j) { acc0[j] = uash2(0u); acc1[j] = uash2(0u); }
            __half2 wprev[5];
            #pragma unroll
            for (int tt = 0; tt < 6; ++tt) {
                unsigned u[9];
                const unsigned* rp = (const unsigned*)(sh + xbase + (2 * i + tt) * 34);
                #pragma unroll
                for (int qq = 0; qq < 9; ++qq) u[qq] = rp[qq];
                __half2 p0[9], p1[8];
                #pragma unroll
                for (int qq = 0; qq < 9; ++qq) p0[qq] = uash2(u[qq]);
                #pragma unroll
                for (int qq = 0; qq < 8; ++qq)
                    p1[qq] = uash2(__builtin_amdgcn_perm(u[qq + 1], u[qq], 0x05040302u));

                if (tt < 5) {
                    __half2 wc[5];
                    #pragma unroll
                    for (int kx = 0; kx < 5; ++kx) wc[kx] = wb[tt * 5 + kx];
                    #pragma unroll
                    for (int j = 0; j < 7; ++j) {
                        acc0[j] = __hfma2(p0[j],     wc[0], acc0[j]);
                        acc0[j] = __hfma2(p1[j],     wc[1], acc0[j]);
                        acc0[j] = __hfma2(p0[j + 1], wc[2], acc0[j]);
                        acc0[j] = __hfma2(p1[j + 1], wc[3], acc0[j]);
                        acc0[j] = __hfma2(p0[j + 2], wc[4], acc0[j]);
                    }
                    if (tt >= 1) {
                        #pragma unroll
                        for (int j = 0; j < 7; ++j) {
                            acc1[j] = __hfma2(p0[j],     wprev[0], acc1[j]);
                            acc1[j] = __hfma2(p1[j],     wprev[1], acc1[j]);
                            acc1[j] = __hfma2(p0[j + 1], wprev[2], acc1[j]);
                            acc1[j] = __hfma2(p1[j + 1], wprev[3], acc1[j]);
                            acc1[j] = __hfma2(p0[j + 2], wprev[4], acc1[j]);
                        }
                    }
                    #pragma unroll
                    for (int kx = 0; kx < 5; ++kx) wprev[kx] = wc[kx];
                } else {    // tt == 5: acc1 only, with w row 4 (in wprev)
                    #pragma unroll
                    for (int j = 0; j < 7; ++j) {
                        acc1[j] = __hfma2(p0[j],     wprev[0], acc1[j]);
                        acc1[j] = __hfma2(p1[j],     wprev[1], acc1[j]);
                        acc1[j] = __hfma2(p0[j + 1], wprev[2], acc1[j]);
                        acc1[j] = __hfma2(p1[j + 1], wprev[3], acc1[j]);
                        acc1[j] = __hfma2(p0[j + 2], wprev[4], acc1[j]);
                    }
                }
            }
            int gi = sub * 3 + m;
            short* dst = sh + P1_S + gi * 1178 + i * 84 + hf * 42 + c;
            #pragma unroll
            for (int j = 0; j < 7; ++j) {
                // fp32 epilogue max (ROCm 7.2 lacks __hmax2/__hmax overloads)
                float a0l = __half2float(__low2half(acc0[j]));
                float a0h = __half2float(__high2half(acc0[j]));
                float a1l = __half2float(__low2half(acc1[j]));
                float a1h = __half2float(__high2half(acc1[j]));
                float v = fmaxf(fmaxf(fmaxf(a0l, a0h), fmaxf(a1l, a1h)), 0.f);
                dst[j * 6] = (short)f2bf(v);
            }
        }
    }
    __syncthreads();

    // ===== conv2 via MFMA, dy-packed: M = img(8) x pool-row dy(2), N=16 oc, K=5x32 =====
    {
        short8 Breg[5];
        #pragma unroll
        for (int s = 0; s < 5; ++s)
            Breg[s] = *(const short8*)(sh + BT_S + cn * 168 + s * 32 + 8 * g);

        for (int e = tid; e < 8 * 24; e += TH) {        // p2 k-pad zeros [400,424)
            int im = e / 24;
            sh[P2_S + im * 424 + 400 + (e - im * 24)] = 0;
        }

        for (int w = wid; w < 25; w += 4) {             // pool windows (i,jx)
            int i = w / 5, jx = w - 5 * i;
            floatx4 a0 = {0.f,0.f,0.f,0.f}, a1 = {0.f,0.f,0.f,0.f};
            #pragma unroll
            for (int s = 0; s < 5; ++s) {
                #pragma unroll
                for (int dxp = 0; dxp < 2; ++dxp) {
                    // A row = cn: img = cn&7, pool-dy = cn>>3 folded into the y offset
                    int as = pr * 1178 + (2 * i + dyr + s) * 84 + (2 * jx + dxp) * 6 + 8 * g;
                    int ai = as >> 1;               // 4B-aligned
                    union { int4 i4; short8 s8; } a;
                    a.i4.x = p1i[ai];     a.i4.y = p1i[ai + 1];
                    a.i4.z = p1i[ai + 2]; a.i4.w = p1i[ai + 3];
                    floatx4* acc = dxp == 0 ? &a0 : &a1;
                    *acc = __builtin_amdgcn_mfma_f32_16x16x32_bf16(a.s8, Breg[s], *acc, 0, 0, 0);
                }
            }
            // pool: in-lane dx max, cross-row dy max (row r vs r+8 = lane xor 32)
            #pragma unroll
            for (int rg = 0; rg < 4; ++rg) {
                float v = fmaxf(a0[rg], a1[rg]);
                v = fmaxf(v, __shfl_xor(v, 32));
                if (g < 2) {
                    int im = 4 * g + rg;
                    sh[P2_S + im * 424 + cn * 25 + i * 5 + jx] = (short)f2bf(fmaxf(v, 0.f));
                }
            }
        }
    }
    __syncthreads();

    // ================= fc1 via MFMA: K=400(13 steps), N=120(8 tiles) =================
    {
        for (int e = tid; e < 8 * 16; e += TH) {        // h1 pad zeros [120,136)
            int im = e >> 4;
            sh[H1_S + im * 136 + 120 + (e & 15)] = 0;
        }
        for (int nt = wid; nt < 8; nt += 4) {
            floatx4 acc = {0.f,0.f,0.f,0.f};
            int n = nt * 16 + cn;
            const float* wrow = fw1 + (size_t)(n < 120 ? n : 119) * 400;
            for (int ks = 0; ks < 13; ++ks) {
                int kb = ks * 32 + 8 * g;
                short8 b = load_bf8t(wrow, kb, 400);
                short8 a = *(const short8*)(sh + P2_S + pr * 424 + kb);
                acc = __builtin_amdgcn_mfma_f32_16x16x32_bf16(a, b, acc, 0, 0, 0);
            }
            if (g < 2 && n < 120) {
                #pragma unroll
                for (int rg = 0; rg < 4; ++rg)
                    sh[H1_S + (4 * g + rg) * 136 + n] = (short)f2bf(fmaxf(acc[rg], 0.f));
            }
        }
    }
    __syncthreads();

    // ================= fc2 via MFMA: K=120(4 steps), N=84(6 tiles) =================
    {
        for (int e = tid; e < 8 * 20; e += TH) {        // h2 pad zeros [84,104)
            int im = e / 20;
            sh[H2_S + im * 104 + 84 + (e - im * 20)] = 0;
        }
        for (int nt = wid; nt < 6; nt += 4) {
            floatx4 acc = {0.f,0.f,0.f,0.f};
            int n = nt * 16 + cn;
            const float* wrow = fw2 + (size_t)(n < 84 ? n : 83) * 120;
            for (int ks = 0; ks < 4; ++ks) {
                int kb = ks * 32 + 8 * g;
                short8 b = load_bf8t(wrow, kb, 120);
                short8 a = *(const short8*)(sh + H1_S + pr * 136 + kb);
                acc = __builtin_amdgcn_mfma_f32_16x16x32_bf16(a, b, acc, 0, 0, 0);
            }
            if (g < 2 && n < 84) {
                #pragma unroll
                for (int rg = 0; rg < 4; ++rg)
                    sh[H2_S + (4 * g + rg) * 104 + n] = (short)f2bf(fmaxf(acc[rg], 0.f));
            }
        }
    }
    __syncthreads();

    // ================= fc3 via MFMA: K=84(3 steps), N=10 + bias =================
    if (wid == 0) {
        floatx4 acc = {0.f,0.f,0.f,0.f};
        int n = cn;
        const float* wrow = fc3w + (size_t)(n < 10 ? n : 9) * 84;
        for (int ks = 0; ks < 3; ++ks) {
            int kb = ks * 32 + 8 * g;
            short8 b = load_bf8t(wrow, kb, 84);
            short8 a = *(const short8*)(sh + H2_S + pr * 104 + kb);
            acc = __builtin_amdgcn_mfma_f32_16x16x32_bf16(a, b, acc, 0, 0, 0);
        }
        if (g < 2 && n < 10) {
            float bias = fc3b[n];
            #pragma unroll
            for (int rg = 0; rg < 4; ++rg)
                sf[LOG_F + (4 * g + rg) * 12 + n] = acc[rg] + bias;
        }
    }
    __syncthreads();

    // ================= softmax, one thread per image =================
    if (tid < 8) {
        const float* lg = sf + LOG_F + tid * 12;
        float mx = lg[0];
        #pragma unroll
        for (int n = 1; n < 10; ++n) mx = fmaxf(mx, lg[n]);
        float e[10]; float sum = 0.f;
        #pragma unroll
        for (int n = 0; n < 10; ++n) { e[n] = expf(lg[n] - mx); sum += e[n]; }
        float inv = 1.f / sum;
        float* op = out + ((size_t)blk * 8 + tid) * 10;
        #pragma unroll
        for (int n = 0; n < 10; ++n) op[n] = e[n] * inv;
    }
}

extern "C" void kernel_launch(void* const* d_in, const int* in_sizes, int n_in,
                              void* d_out, int out_size, void* d_ws, size_t ws_size,
                              hipStream_t stream) {
    const float* x    = (const float*)d_in[0];
    const float* w1   = (const float*)d_in[1];
    const float* w2   = (const float*)d_in[2];
    const float* fw1  = (const float*)d_in[3];
    const float* fw2  = (const float*)d_in[4];
    const float* fc3w = (const float*)d_in[5];
    const float* fc3b = (const float*)d_in[6];
    float* outp = (float*)d_out;

    dim3 grid(16384 / 8), block(TH);
    hipLaunchKernelGGL(lenet_kernel, grid, block, 0, stream,
                       x, w1, w2, fw1, fw2, fc3w, fc3b, outp);
}